// Round 8
// baseline (351.419 us; speedup 1.0000x reference)
//
#include <hip/hip_runtime.h>

// ---------------------------------------------------------------------------
// TransD-style scoring:
//   score[b] = || rp*(hp.h) + sum(h) + r - rp*(tp.t) - sum(t) ||^2
// Algebraic reduction: with a = hp.h - tp.t, c = sum(h) - sum(t):
//   score = a^2*S_pp + c^2*D + S_rr + 2ac*S_p + 2a*S_pr + 2c*S_r
// Pass 1: per-node (sum, dot). Pass 2: per-relation sums. Pass 3: O(1) score.
//
// Kept (measured wins): he/hep normal loads (IC-resident; FETCH == te/tep
// footprint confirms), te/tep non-temporal (pure HBM stream, no IC
// allocation); even/odd wave parity interleave keeps both memory paths
// concurrently active; 32-lane shuffle reduce (DPP variant was slower, R7).
// R8 (new, single variable): persistent grid-stride with 2048 blocks —
// the m13 copy-benchmark launch structure — instead of 50k one-shot blocks.
// Body per iteration is byte-identical to R6. Wave parity is stride-
// invariant, so each wave remains a pure IC-stream or pure HBM-stream and
// the grid's instantaneous footprint is two compact sweeping windows.
// ---------------------------------------------------------------------------

#define ENT_DIM 128

typedef float f4_t __attribute__((ext_vector_type(4)));

__device__ __forceinline__ float4 ldg_nt4(const float* p) {
    f4_t v = __builtin_nontemporal_load((const f4_t*)p);
    return make_float4(v.x, v.y, v.z, v.w);
}

// Pass 1: per-node (sum, dot) for head and tail tables.
// One wave-step = 2 rows: lanes 0-31 -> row 2p, lanes 32-63 -> row 2p+1;
// float4 loads, 2 contiguous 512B segments per instruction. Even waves
// sweep head pairs (normal loads, IC path); odd waves sweep tail pairs
// (nt loads, HBM path). Grid-stride over 2048 blocks.
__global__ __launch_bounds__(256, 8)
void node_stats_kernel(const float* __restrict__ he,
                       const float* __restrict__ hep,
                       const float* __restrict__ te,
                       const float* __restrict__ tep,
                       float2* __restrict__ hstats,
                       float2* __restrict__ tstats,
                       int n_nodes) {
    const int lane   = threadIdx.x & 63;
    const int half   = lane >> 5;       // which of the 2 rows this lane serves
    const int l      = lane & 31;       // float4 index within the row
    const int wave   = (blockIdx.x * blockDim.x + threadIdx.x) >> 6;
    const int nwaves = (gridDim.x * blockDim.x) >> 6;   // even by construction
    const int njobs  = 2 * n_nodes;     // head rows then tail rows
    const int npairs = (njobs + 1) >> 1;
    const int hpairs = (npairs + 1) >> 1;  // pair-space front half = head rows

    for (int vw = wave; vw < npairs; vw += nwaves) {
        // Bijective parity interleave (R6): even vw -> head pair vw/2,
        // odd vw -> tail pair hpairs + vw/2. Parity fixed per wave.
        const int pair = (vw & 1) ? (hpairs + (vw >> 1)) : (vw >> 1);
        const int job  = pair * 2 + half;
        if (job >= njobs) continue;

        float4 v, vp;
        float2* st;
        int node;
        if (job < n_nodes) {
            // Head tables: normal loads -> IC-resident (204.8 MB fits).
            node = job;
            st = hstats;
            v  = ((const float4*)(he  + (size_t)node * ENT_DIM))[l];
            vp = ((const float4*)(hep + (size_t)node * ENT_DIM))[l];
        } else {
            // Tail tables: non-temporal -> pure HBM stream, no IC allocation.
            node = job - n_nodes;
            st = tstats;
            v  = ldg_nt4(te  + (size_t)node * ENT_DIM + 4 * l);
            vp = ldg_nt4(tep + (size_t)node * ENT_DIM + 4 * l);
        }

        float s = (v.x + v.y) + (v.z + v.w);
        float d = v.x * vp.x + v.y * vp.y + v.z * vp.z + v.w * vp.w;

        // reduce within each 32-lane half (xor masks < 32 never cross halves)
        #pragma unroll
        for (int off = 16; off >= 1; off >>= 1) {
            s += __shfl_xor(s, off, 64);
            d += __shfl_xor(d, off, 64);
        }
        if (l == 0) st[node] = make_float2(s, d);
    }
}

// Pass 2: per-relation sums. One wave per relation (only 500).
__global__ void rel_stats_kernel(const float* __restrict__ re,
                                 const float* __restrict__ rep,
                                 float* __restrict__ rstats, int n_rels) {
    const int wave = (blockIdx.x * blockDim.x + threadIdx.x) >> 6;
    const int lane = threadIdx.x & 63;
    if (wave >= n_rels) return;

    const float2 r = ((const float2*)(re  + (size_t)wave * ENT_DIM))[lane];
    const float2 p = ((const float2*)(rep + (size_t)wave * ENT_DIM))[lane];
    float s_pp = p.x * p.x + p.y * p.y;
    float s_p  = p.x + p.y;
    float s_pr = p.x * r.x + p.y * r.y;
    float s_r  = r.x + r.y;
    float s_rr = r.x * r.x + r.y * r.y;
    #pragma unroll
    for (int off = 32; off >= 1; off >>= 1) {
        s_pp += __shfl_xor(s_pp, off, 64);
        s_p  += __shfl_xor(s_p,  off, 64);
        s_pr += __shfl_xor(s_pr, off, 64);
        s_r  += __shfl_xor(s_r,  off, 64);
        s_rr += __shfl_xor(s_rr, off, 64);
    }
    if (lane == 0) {
        float* o = rstats + (size_t)wave * 8;   // 32B stride per relation
        o[0] = s_pp; o[1] = s_p; o[2] = s_pr; o[3] = s_r; o[4] = s_rr;
    }
}

// Pass 3 (frozen at R2 config): 2 batch elements per thread; int2 idx loads;
// rstats in LDS stride-9 (random ri covers all 32 banks); 4 independent
// L2-resident 8B gathers in flight per thread.
__global__ void score_kernel(const int* __restrict__ hidx,
                             const int* __restrict__ tidx,
                             const int* __restrict__ ridx,
                             const float2* __restrict__ hstats,
                             const float2* __restrict__ tstats,
                             const float* __restrict__ rstats,
                             float* __restrict__ out, int B, int n_rels) {
    extern __shared__ float rs[];   // n_rels * 9 floats
    for (int i = threadIdx.x; i < n_rels * 2; i += blockDim.x) {
        const float4 v = ((const float4*)rstats)[i];
        const int base = (i >> 1) * 9 + (i & 1) * 4;
        rs[base]     = v.x;
        rs[base + 1] = v.y;
        rs[base + 2] = v.z;
        rs[base + 3] = v.w;
    }
    __syncthreads();

    const int g  = blockIdx.x * blockDim.x + threadIdx.x;
    const int b0 = 2 * g;
    if (b0 >= B) return;

    if (b0 + 1 < B) {
        const int2 hi = ((const int2*)hidx)[g];
        const int2 ti = ((const int2*)tidx)[g];
        const int2 ri = ((const int2*)ridx)[g];
        const float2 hs0 = hstats[hi.x];
        const float2 hs1 = hstats[hi.y];
        const float2 ts0 = tstats[ti.x];
        const float2 ts1 = tstats[ti.y];

        const float c0 = hs0.x - ts0.x, a0 = hs0.y - ts0.y;
        const float c1 = hs1.x - ts1.x, a1 = hs1.y - ts1.y;
        const float* q0 = rs + ri.x * 9;
        const float* q1 = rs + ri.y * 9;
        const float sc0 = a0 * a0 * q0[0] + c0 * c0 * (float)ENT_DIM + q0[4]
                        + 2.0f * (a0 * c0 * q0[1] + a0 * q0[2] + c0 * q0[3]);
        const float sc1 = a1 * a1 * q1[0] + c1 * c1 * (float)ENT_DIM + q1[4]
                        + 2.0f * (a1 * c1 * q1[1] + a1 * q1[2] + c1 * q1[3]);
        ((float2*)out)[g] = make_float2(sc0, sc1);
    } else {
        const int hi = hidx[b0], ti = tidx[b0], ri = ridx[b0];
        const float2 hs = hstats[hi];
        const float2 ts = tstats[ti];
        const float c = hs.x - ts.x, a = hs.y - ts.y;
        const float* q = rs + ri * 9;
        out[b0] = a * a * q[0] + c * c * (float)ENT_DIM + q[4]
                + 2.0f * (a * c * q[1] + a * q[2] + c * q[3]);
    }
}

// Fallback (only if ws_size is too small): direct wave-per-element compute.
__global__ void direct_kernel(const float* __restrict__ he, const float* __restrict__ hep,
                              const float* __restrict__ te, const float* __restrict__ tep,
                              const float* __restrict__ re, const float* __restrict__ rep,
                              const int* __restrict__ hidx, const int* __restrict__ tidx,
                              const int* __restrict__ ridx,
                              float* __restrict__ out, int B) {
    const int wave = (blockIdx.x * blockDim.x + threadIdx.x) >> 6;
    const int lane = threadIdx.x & 63;
    if (wave >= B) return;
    const int hi = hidx[wave], ti = tidx[wave], ri = ridx[wave];
    const float2 h  = ((const float2*)(he  + (size_t)hi * ENT_DIM))[lane];
    const float2 hp = ((const float2*)(hep + (size_t)hi * ENT_DIM))[lane];
    const float2 t  = ((const float2*)(te  + (size_t)ti * ENT_DIM))[lane];
    const float2 tp = ((const float2*)(tep + (size_t)ti * ENT_DIM))[lane];
    const float2 r  = ((const float2*)(re  + (size_t)ri * ENT_DIM))[lane];
    const float2 rp = ((const float2*)(rep + (size_t)ri * ENT_DIM))[lane];
    float hd = h.x * hp.x + h.y * hp.y;
    float hs = h.x + h.y;
    float td = t.x * tp.x + t.y * tp.y;
    float ts = t.x + t.y;
    #pragma unroll
    for (int off = 32; off >= 1; off >>= 1) {
        hd += __shfl_xor(hd, off, 64);
        hs += __shfl_xor(hs, off, 64);
        td += __shfl_xor(td, off, 64);
        ts += __shfl_xor(ts, off, 64);
    }
    const float a = hd - td, c = hs - ts;
    const float dx = a * rp.x + c + r.x;
    const float dy = a * rp.y + c + r.y;
    float sc = dx * dx + dy * dy;
    #pragma unroll
    for (int off = 32; off >= 1; off >>= 1) sc += __shfl_xor(sc, off, 64);
    if (lane == 0) out[wave] = sc;
}

extern "C" void kernel_launch(void* const* d_in, const int* in_sizes, int n_in,
                              void* d_out, int out_size, void* d_ws, size_t ws_size,
                              hipStream_t stream) {
    const float* he  = (const float*)d_in[0];
    const float* hep = (const float*)d_in[1];
    const float* te  = (const float*)d_in[2];
    const float* tep = (const float*)d_in[3];
    const float* re  = (const float*)d_in[4];
    const float* rep = (const float*)d_in[5];
    const int* hidx  = (const int*)d_in[6];
    const int* tidx  = (const int*)d_in[7];
    const int* ridx  = (const int*)d_in[8];
    float* out = (float*)d_out;

    const int n_nodes = in_sizes[0] / ENT_DIM;   // 200000
    const int n_rels  = in_sizes[4] / ENT_DIM;   // 500
    const int B       = in_sizes[6];             // 500000

    const size_t hstats_bytes = (size_t)n_nodes * sizeof(float2);
    const size_t rstats_bytes = (size_t)n_rels * 8 * sizeof(float);
    const size_t need = 2 * hstats_bytes + rstats_bytes;
    const size_t lds_bytes = (size_t)n_rels * 9 * sizeof(float);

    if (ws_size >= need && lds_bytes <= 60 * 1024) {
        float2* hstats = (float2*)d_ws;
        float2* tstats = (float2*)((char*)d_ws + hstats_bytes);
        float*  rstats = (float*)((char*)d_ws + 2 * hstats_bytes);

        // Pass 1: persistent grid-stride, m13 launch shape: 2048 blocks
        // (8 blocks/CU, 32 waves/CU at VGPR~16), each wave sweeps ~24
        // row-pairs with a stride-invariant stream parity.
        const int npairs  = n_nodes;                 // 2*n_nodes rows / 2
        int blocks1 = (npairs + 3) / 4;
        if (blocks1 > 2048) blocks1 = 2048;
        node_stats_kernel<<<blocks1, 256, 0, stream>>>(he, hep, te, tep,
                                                       hstats, tstats, n_nodes);
        // Pass 2
        const int blocks2 = (n_rels * 64 + 255) / 256;
        rel_stats_kernel<<<blocks2, 256, 0, stream>>>(re, rep, rstats, n_rels);
        // Pass 3: 2 elements per thread.
        const int nthreads = (B + 1) / 2;
        const int blocks3  = (nthreads + 255) / 256;
        score_kernel<<<blocks3, 256, lds_bytes, stream>>>(hidx, tidx, ridx,
                                                          hstats, tstats, rstats,
                                                          out, B, n_rels);
    } else {
        const int blocks = (B * 64 + 255) / 256;
        direct_kernel<<<blocks, 256, 0, stream>>>(he, hep, te, tep, re, rep,
                                                  hidx, tidx, ridx, out, B);
    }
}

// Round 9
// 338.694 us; speedup vs baseline: 1.0376x; 1.0376x over previous
//
#include <hip/hip_runtime.h>

// ---------------------------------------------------------------------------
// TransD-style scoring:
//   score[b] = || rp*(hp.h) + sum(h) + r - rp*(tp.t) - sum(t) ||^2
// Algebraic reduction: with a = hp.h - tp.t, c = sum(h) - sum(t):
//   score = a^2*S_pp + c^2*D + S_rr + 2ac*S_p + 2a*S_pr + 2c*S_r
// Pass 1: per-node (sum, dot). Pass 2: per-relation sums. Pass 3: O(1) score.
//
// R9 experiment (single variable vs R6): ALL tables non-temporal.
// R6 counters showed the half-nt partition runs IC-stream ~2.1 TB/s +
// HBM-stream ~2.1 TB/s; the HBM path had no CU-side reason to cap at 2.1,
// implicating IC-hit service rate (~2 TB/s) as the slow partner. If so, the
// best config bypasses IC entirely: one pure HBM read stream (m13 regime,
// 6.29 TB/s measured on this chip). Structure otherwise byte-identical to
// R6: one-shot waves (persistence regressed twice), 2 rows/wave, 2x512B
// segments/instr, parity interleave of the he/hep vs te/tep windows,
// 32-lane shuffle reduce (DPP was slower).
// ---------------------------------------------------------------------------

#define ENT_DIM 128

typedef float f4_t __attribute__((ext_vector_type(4)));

__device__ __forceinline__ float4 ldg_nt4(const float* p) {
    f4_t v = __builtin_nontemporal_load((const f4_t*)p);
    return make_float4(v.x, v.y, v.z, v.w);
}

// Pass 1: per-node (sum, dot) for head and tail tables.
// One wave handles 2 rows: lanes 0-31 -> row 2p, lanes 32-63 -> row 2p+1;
// float4 nt loads, 2 contiguous 512B segments per instruction. Even waves
// sweep head pairs, odd waves sweep tail pairs (two compact HBM windows).
__global__ void node_stats_kernel(const float* __restrict__ he,
                                  const float* __restrict__ hep,
                                  const float* __restrict__ te,
                                  const float* __restrict__ tep,
                                  float2* __restrict__ hstats,
                                  float2* __restrict__ tstats,
                                  int n_nodes) {
    const int wave  = (blockIdx.x * blockDim.x + threadIdx.x) >> 6;
    const int lane  = threadIdx.x & 63;
    const int half  = lane >> 5;      // which of the 2 rows this lane serves
    const int l     = lane & 31;      // float4 index within the row
    const int npairs = n_nodes;       // 2*n_nodes rows / 2 rows per pair
    const int njobs  = 2 * n_nodes;

    if (wave >= npairs) return;
    // Bijective interleave: even wave -> pair wave/2 (head rows),
    // odd wave -> pair ceil(npairs/2)+wave/2 (tail rows).
    const int pair = (wave & 1) ? (((npairs + 1) >> 1) + (wave >> 1))
                                : (wave >> 1);
    const int job = pair * 2 + half;
    if (job >= njobs) return;

    float4 v, vp;
    float2* st;
    int node;
    if (job < n_nodes) {
        node = job;
        st = hstats;
        v  = ldg_nt4(he  + (size_t)node * ENT_DIM + 4 * l);
        vp = ldg_nt4(hep + (size_t)node * ENT_DIM + 4 * l);
    } else {
        node = job - n_nodes;
        st = tstats;
        v  = ldg_nt4(te  + (size_t)node * ENT_DIM + 4 * l);
        vp = ldg_nt4(tep + (size_t)node * ENT_DIM + 4 * l);
    }

    float s = (v.x + v.y) + (v.z + v.w);
    float d = v.x * vp.x + v.y * vp.y + v.z * vp.z + v.w * vp.w;

    // reduce within each 32-lane half (xor masks < 32 never cross halves)
    #pragma unroll
    for (int off = 16; off >= 1; off >>= 1) {
        s += __shfl_xor(s, off, 64);
        d += __shfl_xor(d, off, 64);
    }
    if (l == 0) st[node] = make_float2(s, d);
}

// Pass 2: per-relation sums. One wave per relation (only 500).
__global__ void rel_stats_kernel(const float* __restrict__ re,
                                 const float* __restrict__ rep,
                                 float* __restrict__ rstats, int n_rels) {
    const int wave = (blockIdx.x * blockDim.x + threadIdx.x) >> 6;
    const int lane = threadIdx.x & 63;
    if (wave >= n_rels) return;

    const float2 r = ((const float2*)(re  + (size_t)wave * ENT_DIM))[lane];
    const float2 p = ((const float2*)(rep + (size_t)wave * ENT_DIM))[lane];
    float s_pp = p.x * p.x + p.y * p.y;
    float s_p  = p.x + p.y;
    float s_pr = p.x * r.x + p.y * r.y;
    float s_r  = r.x + r.y;
    float s_rr = r.x * r.x + r.y * r.y;
    #pragma unroll
    for (int off = 32; off >= 1; off >>= 1) {
        s_pp += __shfl_xor(s_pp, off, 64);
        s_p  += __shfl_xor(s_p,  off, 64);
        s_pr += __shfl_xor(s_pr, off, 64);
        s_r  += __shfl_xor(s_r,  off, 64);
        s_rr += __shfl_xor(s_rr, off, 64);
    }
    if (lane == 0) {
        float* o = rstats + (size_t)wave * 8;   // 32B stride per relation
        o[0] = s_pp; o[1] = s_p; o[2] = s_pr; o[3] = s_r; o[4] = s_rr;
    }
}

// Pass 3 (frozen at R2 config): 2 batch elements per thread; int2 idx loads;
// rstats in LDS stride-9 (random ri covers all 32 banks); 4 independent
// L2-resident 8B gathers in flight per thread.
__global__ void score_kernel(const int* __restrict__ hidx,
                             const int* __restrict__ tidx,
                             const int* __restrict__ ridx,
                             const float2* __restrict__ hstats,
                             const float2* __restrict__ tstats,
                             const float* __restrict__ rstats,
                             float* __restrict__ out, int B, int n_rels) {
    extern __shared__ float rs[];   // n_rels * 9 floats
    for (int i = threadIdx.x; i < n_rels * 2; i += blockDim.x) {
        const float4 v = ((const float4*)rstats)[i];
        const int base = (i >> 1) * 9 + (i & 1) * 4;
        rs[base]     = v.x;
        rs[base + 1] = v.y;
        rs[base + 2] = v.z;
        rs[base + 3] = v.w;
    }
    __syncthreads();

    const int g  = blockIdx.x * blockDim.x + threadIdx.x;
    const int b0 = 2 * g;
    if (b0 >= B) return;

    if (b0 + 1 < B) {
        const int2 hi = ((const int2*)hidx)[g];
        const int2 ti = ((const int2*)tidx)[g];
        const int2 ri = ((const int2*)ridx)[g];
        const float2 hs0 = hstats[hi.x];
        const float2 hs1 = hstats[hi.y];
        const float2 ts0 = tstats[ti.x];
        const float2 ts1 = tstats[ti.y];

        const float c0 = hs0.x - ts0.x, a0 = hs0.y - ts0.y;
        const float c1 = hs1.x - ts1.x, a1 = hs1.y - ts1.y;
        const float* q0 = rs + ri.x * 9;
        const float* q1 = rs + ri.y * 9;
        const float sc0 = a0 * a0 * q0[0] + c0 * c0 * (float)ENT_DIM + q0[4]
                        + 2.0f * (a0 * c0 * q0[1] + a0 * q0[2] + c0 * q0[3]);
        const float sc1 = a1 * a1 * q1[0] + c1 * c1 * (float)ENT_DIM + q1[4]
                        + 2.0f * (a1 * c1 * q1[1] + a1 * q1[2] + c1 * q1[3]);
        ((float2*)out)[g] = make_float2(sc0, sc1);
    } else {
        const int hi = hidx[b0], ti = tidx[b0], ri = ridx[b0];
        const float2 hs = hstats[hi];
        const float2 ts = tstats[ti];
        const float c = hs.x - ts.x, a = hs.y - ts.y;
        const float* q = rs + ri * 9;
        out[b0] = a * a * q[0] + c * c * (float)ENT_DIM + q[4]
                + 2.0f * (a * c * q[1] + a * q[2] + c * q[3]);
    }
}

// Fallback (only if ws_size is too small): direct wave-per-element compute.
__global__ void direct_kernel(const float* __restrict__ he, const float* __restrict__ hep,
                              const float* __restrict__ te, const float* __restrict__ tep,
                              const float* __restrict__ re, const float* __restrict__ rep,
                              const int* __restrict__ hidx, const int* __restrict__ tidx,
                              const int* __restrict__ ridx,
                              float* __restrict__ out, int B) {
    const int wave = (blockIdx.x * blockDim.x + threadIdx.x) >> 6;
    const int lane = threadIdx.x & 63;
    if (wave >= B) return;
    const int hi = hidx[wave], ti = tidx[wave], ri = ridx[wave];
    const float2 h  = ((const float2*)(he  + (size_t)hi * ENT_DIM))[lane];
    const float2 hp = ((const float2*)(hep + (size_t)hi * ENT_DIM))[lane];
    const float2 t  = ((const float2*)(te  + (size_t)ti * ENT_DIM))[lane];
    const float2 tp = ((const float2*)(tep + (size_t)ti * ENT_DIM))[lane];
    const float2 r  = ((const float2*)(re  + (size_t)ri * ENT_DIM))[lane];
    const float2 rp = ((const float2*)(rep + (size_t)ri * ENT_DIM))[lane];
    float hd = h.x * hp.x + h.y * hp.y;
    float hs = h.x + h.y;
    float td = t.x * tp.x + t.y * tp.y;
    float ts = t.x + t.y;
    #pragma unroll
    for (int off = 32; off >= 1; off >>= 1) {
        hd += __shfl_xor(hd, off, 64);
        hs += __shfl_xor(hs, off, 64);
        td += __shfl_xor(td, off, 64);
        ts += __shfl_xor(ts, off, 64);
    }
    const float a = hd - td, c = hs - ts;
    const float dx = a * rp.x + c + r.x;
    const float dy = a * rp.y + c + r.y;
    float sc = dx * dx + dy * dy;
    #pragma unroll
    for (int off = 32; off >= 1; off >>= 1) sc += __shfl_xor(sc, off, 64);
    if (lane == 0) out[wave] = sc;
}

extern "C" void kernel_launch(void* const* d_in, const int* in_sizes, int n_in,
                              void* d_out, int out_size, void* d_ws, size_t ws_size,
                              hipStream_t stream) {
    const float* he  = (const float*)d_in[0];
    const float* hep = (const float*)d_in[1];
    const float* te  = (const float*)d_in[2];
    const float* tep = (const float*)d_in[3];
    const float* re  = (const float*)d_in[4];
    const float* rep = (const float*)d_in[5];
    const int* hidx  = (const int*)d_in[6];
    const int* tidx  = (const int*)d_in[7];
    const int* ridx  = (const int*)d_in[8];
    float* out = (float*)d_out;

    const int n_nodes = in_sizes[0] / ENT_DIM;   // 200000
    const int n_rels  = in_sizes[4] / ENT_DIM;   // 500
    const int B       = in_sizes[6];             // 500000

    const size_t hstats_bytes = (size_t)n_nodes * sizeof(float2);
    const size_t rstats_bytes = (size_t)n_rels * 8 * sizeof(float);
    const size_t need = 2 * hstats_bytes + rstats_bytes;
    const size_t lds_bytes = (size_t)n_rels * 9 * sizeof(float);

    if (ws_size >= need && lds_bytes <= 60 * 1024) {
        float2* hstats = (float2*)d_ws;
        float2* tstats = (float2*)((char*)d_ws + hstats_bytes);
        float*  rstats = (float*)((char*)d_ws + 2 * hstats_bytes);

        // Pass 1: 2*n_nodes rows, 2 rows/wave, 4 waves/block, one-shot.
        const int waves1  = n_nodes;                  // (2*n_nodes jobs)/2
        const int blocks1 = (waves1 + 3) / 4;
        node_stats_kernel<<<blocks1, 256, 0, stream>>>(he, hep, te, tep,
                                                       hstats, tstats, n_nodes);
        // Pass 2
        const int blocks2 = (n_rels * 64 + 255) / 256;
        rel_stats_kernel<<<blocks2, 256, 0, stream>>>(re, rep, rstats, n_rels);
        // Pass 3: 2 elements per thread.
        const int nthreads = (B + 1) / 2;
        const int blocks3  = (nthreads + 255) / 256;
        score_kernel<<<blocks3, 256, lds_bytes, stream>>>(hidx, tidx, ridx,
                                                          hstats, tstats, rstats,
                                                          out, B, n_rels);
    } else {
        const int blocks = (B * 64 + 255) / 256;
        direct_kernel<<<blocks, 256, 0, stream>>>(he, hep, te, tep, re, rep,
                                                  hidx, tidx, ridx, out, B);
    }
}

// Round 10
// 331.046 us; speedup vs baseline: 1.0615x; 1.0231x over previous
//
#include <hip/hip_runtime.h>

// ---------------------------------------------------------------------------
// TransD-style scoring:
//   score[b] = || rp*(hp.h) + sum(h) + r - rp*(tp.t) - sum(t) ||^2
// Algebraic reduction: with a = hp.h - tp.t, c = sum(h) - sum(t):
//   score = a^2*S_pp + c^2*D + S_rr + 2ac*S_p + 2a*S_pr + 2c*S_r
// Pass 1: per-node (sum, dot). Pass 2: per-relation sums. Pass 3: O(1) score.
//
// Final structure (R10). Measured findings that got here:
//  - ALL table loads non-temporal: IC-hit service rate (~2 TB/s) was the
//    bottleneck; pure HBM streaming runs 5.6 TB/s logical (R9: 97->73us).
//  - One-shot waves, 2 rows/wave, 2x512B contiguous segments per load instr
//    (R0 mapping): beat 8x128B strided (R1), persistent grids (R3/R8), and
//    4-consecutive-row footprints (R4).
//  - 32-lane shuffle reduce: beat DPP row_shr chains (R7).
//  - R10: parity permute removed — it existed to interleave the IC stream
//    with the HBM stream (R6); with all-nt there is no IC stream, so the
//    linear sweep is strictly simpler and keeps the footprint compact.
//  - score: rstats in LDS stride-9, 2 elem/thread, int2 idx loads (R2).
// ---------------------------------------------------------------------------

#define ENT_DIM 128

typedef float f4_t __attribute__((ext_vector_type(4)));

__device__ __forceinline__ float4 ldg_nt4(const float* p) {
    f4_t v = __builtin_nontemporal_load((const f4_t*)p);
    return make_float4(v.x, v.y, v.z, v.w);
}

// Pass 1: per-node (sum, dot) for head and tail tables.
// One wave handles 2 rows: lanes 0-31 -> row 2w, lanes 32-63 -> row 2w+1;
// float4 nt loads, 2 contiguous 512B segments per instruction.
__global__ void node_stats_kernel(const float* __restrict__ he,
                                  const float* __restrict__ hep,
                                  const float* __restrict__ te,
                                  const float* __restrict__ tep,
                                  float2* __restrict__ hstats,
                                  float2* __restrict__ tstats,
                                  int n_nodes) {
    const int wave  = (blockIdx.x * blockDim.x + threadIdx.x) >> 6;
    const int lane  = threadIdx.x & 63;
    const int half  = lane >> 5;      // which of the 2 rows this lane serves
    const int l     = lane & 31;      // float4 index within the row
    const int njobs = 2 * n_nodes;    // head rows then tail rows

    const int job = wave * 2 + half;
    if (job >= njobs) return;

    float4 v, vp;
    float2* st;
    int node;
    if (job < n_nodes) {
        node = job;
        st = hstats;
        v  = ldg_nt4(he  + (size_t)node * ENT_DIM + 4 * l);
        vp = ldg_nt4(hep + (size_t)node * ENT_DIM + 4 * l);
    } else {
        node = job - n_nodes;
        st = tstats;
        v  = ldg_nt4(te  + (size_t)node * ENT_DIM + 4 * l);
        vp = ldg_nt4(tep + (size_t)node * ENT_DIM + 4 * l);
    }

    float s = (v.x + v.y) + (v.z + v.w);
    float d = v.x * vp.x + v.y * vp.y + v.z * vp.z + v.w * vp.w;

    // reduce within each 32-lane half (xor masks < 32 never cross halves)
    #pragma unroll
    for (int off = 16; off >= 1; off >>= 1) {
        s += __shfl_xor(s, off, 64);
        d += __shfl_xor(d, off, 64);
    }
    if (l == 0) st[node] = make_float2(s, d);
}

// Pass 2: per-relation sums. One wave per relation (only 500).
__global__ void rel_stats_kernel(const float* __restrict__ re,
                                 const float* __restrict__ rep,
                                 float* __restrict__ rstats, int n_rels) {
    const int wave = (blockIdx.x * blockDim.x + threadIdx.x) >> 6;
    const int lane = threadIdx.x & 63;
    if (wave >= n_rels) return;

    const float2 r = ((const float2*)(re  + (size_t)wave * ENT_DIM))[lane];
    const float2 p = ((const float2*)(rep + (size_t)wave * ENT_DIM))[lane];
    float s_pp = p.x * p.x + p.y * p.y;
    float s_p  = p.x + p.y;
    float s_pr = p.x * r.x + p.y * r.y;
    float s_r  = r.x + r.y;
    float s_rr = r.x * r.x + r.y * r.y;
    #pragma unroll
    for (int off = 32; off >= 1; off >>= 1) {
        s_pp += __shfl_xor(s_pp, off, 64);
        s_p  += __shfl_xor(s_p,  off, 64);
        s_pr += __shfl_xor(s_pr, off, 64);
        s_r  += __shfl_xor(s_r,  off, 64);
        s_rr += __shfl_xor(s_rr, off, 64);
    }
    if (lane == 0) {
        float* o = rstats + (size_t)wave * 8;   // 32B stride per relation
        o[0] = s_pp; o[1] = s_p; o[2] = s_pr; o[3] = s_r; o[4] = s_rr;
    }
}

// Pass 3 (frozen at R2 config): 2 batch elements per thread; int2 idx loads;
// rstats in LDS stride-9 (random ri covers all 32 banks); 4 independent
// L2-resident 8B gathers in flight per thread.
__global__ void score_kernel(const int* __restrict__ hidx,
                             const int* __restrict__ tidx,
                             const int* __restrict__ ridx,
                             const float2* __restrict__ hstats,
                             const float2* __restrict__ tstats,
                             const float* __restrict__ rstats,
                             float* __restrict__ out, int B, int n_rels) {
    extern __shared__ float rs[];   // n_rels * 9 floats
    for (int i = threadIdx.x; i < n_rels * 2; i += blockDim.x) {
        const float4 v = ((const float4*)rstats)[i];
        const int base = (i >> 1) * 9 + (i & 1) * 4;
        rs[base]     = v.x;
        rs[base + 1] = v.y;
        rs[base + 2] = v.z;
        rs[base + 3] = v.w;
    }
    __syncthreads();

    const int g  = blockIdx.x * blockDim.x + threadIdx.x;
    const int b0 = 2 * g;
    if (b0 >= B) return;

    if (b0 + 1 < B) {
        const int2 hi = ((const int2*)hidx)[g];
        const int2 ti = ((const int2*)tidx)[g];
        const int2 ri = ((const int2*)ridx)[g];
        const float2 hs0 = hstats[hi.x];
        const float2 hs1 = hstats[hi.y];
        const float2 ts0 = tstats[ti.x];
        const float2 ts1 = tstats[ti.y];

        const float c0 = hs0.x - ts0.x, a0 = hs0.y - ts0.y;
        const float c1 = hs1.x - ts1.x, a1 = hs1.y - ts1.y;
        const float* q0 = rs + ri.x * 9;
        const float* q1 = rs + ri.y * 9;
        const float sc0 = a0 * a0 * q0[0] + c0 * c0 * (float)ENT_DIM + q0[4]
                        + 2.0f * (a0 * c0 * q0[1] + a0 * q0[2] + c0 * q0[3]);
        const float sc1 = a1 * a1 * q1[0] + c1 * c1 * (float)ENT_DIM + q1[4]
                        + 2.0f * (a1 * c1 * q1[1] + a1 * q1[2] + c1 * q1[3]);
        ((float2*)out)[g] = make_float2(sc0, sc1);
    } else {
        const int hi = hidx[b0], ti = tidx[b0], ri = ridx[b0];
        const float2 hs = hstats[hi];
        const float2 ts = tstats[ti];
        const float c = hs.x - ts.x, a = hs.y - ts.y;
        const float* q = rs + ri * 9;
        out[b0] = a * a * q[0] + c * c * (float)ENT_DIM + q[4]
                + 2.0f * (a * c * q[1] + a * q[2] + c * q[3]);
    }
}

// Fallback (only if ws_size is too small): direct wave-per-element compute.
__global__ void direct_kernel(const float* __restrict__ he, const float* __restrict__ hep,
                              const float* __restrict__ te, const float* __restrict__ tep,
                              const float* __restrict__ re, const float* __restrict__ rep,
                              const int* __restrict__ hidx, const int* __restrict__ tidx,
                              const int* __restrict__ ridx,
                              float* __restrict__ out, int B) {
    const int wave = (blockIdx.x * blockDim.x + threadIdx.x) >> 6;
    const int lane = threadIdx.x & 63;
    if (wave >= B) return;
    const int hi = hidx[wave], ti = tidx[wave], ri = ridx[wave];
    const float2 h  = ((const float2*)(he  + (size_t)hi * ENT_DIM))[lane];
    const float2 hp = ((const float2*)(hep + (size_t)hi * ENT_DIM))[lane];
    const float2 t  = ((const float2*)(te  + (size_t)ti * ENT_DIM))[lane];
    const float2 tp = ((const float2*)(tep + (size_t)ti * ENT_DIM))[lane];
    const float2 r  = ((const float2*)(re  + (size_t)ri * ENT_DIM))[lane];
    const float2 rp = ((const float2*)(rep + (size_t)ri * ENT_DIM))[lane];
    float hd = h.x * hp.x + h.y * hp.y;
    float hs = h.x + h.y;
    float td = t.x * tp.x + t.y * tp.y;
    float ts = t.x + t.y;
    #pragma unroll
    for (int off = 32; off >= 1; off >>= 1) {
        hd += __shfl_xor(hd, off, 64);
        hs += __shfl_xor(hs, off, 64);
        td += __shfl_xor(td, off, 64);
        ts += __shfl_xor(ts, off, 64);
    }
    const float a = hd - td, c = hs - ts;
    const float dx = a * rp.x + c + r.x;
    const float dy = a * rp.y + c + r.y;
    float sc = dx * dx + dy * dy;
    #pragma unroll
    for (int off = 32; off >= 1; off >>= 1) sc += __shfl_xor(sc, off, 64);
    if (lane == 0) out[wave] = sc;
}

extern "C" void kernel_launch(void* const* d_in, const int* in_sizes, int n_in,
                              void* d_out, int out_size, void* d_ws, size_t ws_size,
                              hipStream_t stream) {
    const float* he  = (const float*)d_in[0];
    const float* hep = (const float*)d_in[1];
    const float* te  = (const float*)d_in[2];
    const float* tep = (const float*)d_in[3];
    const float* re  = (const float*)d_in[4];
    const float* rep = (const float*)d_in[5];
    const int* hidx  = (const int*)d_in[6];
    const int* tidx  = (const int*)d_in[7];
    const int* ridx  = (const int*)d_in[8];
    float* out = (float*)d_out;

    const int n_nodes = in_sizes[0] / ENT_DIM;   // 200000
    const int n_rels  = in_sizes[4] / ENT_DIM;   // 500
    const int B       = in_sizes[6];             // 500000

    const size_t hstats_bytes = (size_t)n_nodes * sizeof(float2);
    const size_t rstats_bytes = (size_t)n_rels * 8 * sizeof(float);
    const size_t need = 2 * hstats_bytes + rstats_bytes;
    const size_t lds_bytes = (size_t)n_rels * 9 * sizeof(float);

    if (ws_size >= need && lds_bytes <= 60 * 1024) {
        float2* hstats = (float2*)d_ws;
        float2* tstats = (float2*)((char*)d_ws + hstats_bytes);
        float*  rstats = (float*)((char*)d_ws + 2 * hstats_bytes);

        // Pass 1: 2*n_nodes rows, 2 rows/wave, 4 waves/block, one-shot.
        const int waves1  = n_nodes;                  // (2*n_nodes jobs)/2
        const int blocks1 = (waves1 + 3) / 4;
        node_stats_kernel<<<blocks1, 256, 0, stream>>>(he, hep, te, tep,
                                                       hstats, tstats, n_nodes);
        // Pass 2
        const int blocks2 = (n_rels * 64 + 255) / 256;
        rel_stats_kernel<<<blocks2, 256, 0, stream>>>(re, rep, rstats, n_rels);
        // Pass 3: 2 elements per thread.
        const int nthreads = (B + 1) / 2;
        const int blocks3  = (nthreads + 255) / 256;
        score_kernel<<<blocks3, 256, lds_bytes, stream>>>(hidx, tidx, ridx,
                                                          hstats, tstats, rstats,
                                                          out, B, n_rels);
    } else {
        const int blocks = (B * 64 + 255) / 256;
        direct_kernel<<<blocks, 256, 0, stream>>>(he, hep, te, tep, re, rep,
                                                  hidx, tidx, ridx, out, B);
    }
}